// Round 1
// baseline (7787.994 us; speedup 1.0000x reference)
//
#include <hip/hip_runtime.h>
#include <math.h>

// Problem constants
#define Bsz 512
#define Nn  24
#define Tt  25
// IN=8, L=64, H=256, OUT=128; in0 = 72

// ---------------------------------------------------------------------------
// Generic 2-input block-diagonal-per-node GEMM:
//   Y[b,n,o] = sum_k A1[b,n,k]*W1[n,k,o] (+ sum_k A2[b,n,k]*W2[n,k,o]) + bias[n,o]
// A layout: (B, N, K) contiguous. W layout: (N, K, O) (or shared (K,O)).
// tanhA1: apply tanhf to A1 elements on load (for yi = tanh(h2)).
// Block: 16x16 threads, 64x64 output tile, 4x4 per-thread microtile.
// ---------------------------------------------------------------------------
__global__ __launch_bounds__(256) void gemm2in(
    const float* __restrict__ A1, int K1,
    const float* __restrict__ A2, int K2,
    const float* __restrict__ W1, const float* __restrict__ W2,
    const float* __restrict__ bias,
    float* __restrict__ Y, int O, int sharedwb, int tanhA1)
{
    const int n  = blockIdx.z;
    const int b0 = blockIdx.y * 64;
    const int o0 = blockIdx.x * 64;
    __shared__ float sA[16][68];
    __shared__ float sW[16][68];
    float acc[4][4];
#pragma unroll
    for (int i = 0; i < 4; i++)
#pragma unroll
        for (int j = 0; j < 4; j++) acc[i][j] = 0.f;
    const int tid = threadIdx.y * 16 + threadIdx.x;

    // ---- pass 1: A1 * W1 ----
    {
        const float* Wb = sharedwb ? W1 : (W1 + (size_t)n * K1 * O);
        for (int k0 = 0; k0 < K1; k0 += 16) {
            for (int i = tid; i < 1024; i += 256) {
                int kk = i & 15, bb = i >> 4;
                int k = k0 + kk;
                float v = 0.f;
                if (k < K1) {
                    v = A1[((size_t)(b0 + bb) * Nn + n) * K1 + k];
                    if (tanhA1) v = tanhf(v);
                }
                sA[kk][bb] = v;
            }
            for (int i = tid; i < 1024; i += 256) {
                int oo = i & 63, kk = i >> 6;
                int k = k0 + kk;
                sW[kk][oo] = (k < K1) ? Wb[(size_t)k * O + o0 + oo] : 0.f;
            }
            __syncthreads();
#pragma unroll
            for (int kk = 0; kk < 16; kk++) {
                float a[4], w[4];
#pragma unroll
                for (int i = 0; i < 4; i++) a[i] = sA[kk][threadIdx.y + i * 16];
#pragma unroll
                for (int j = 0; j < 4; j++) w[j] = sW[kk][threadIdx.x + j * 16];
#pragma unroll
                for (int i = 0; i < 4; i++)
#pragma unroll
                    for (int j = 0; j < 4; j++) acc[i][j] += a[i] * w[j];
            }
            __syncthreads();
        }
    }
    // ---- pass 2: A2 * W2 (node-wise weights always) ----
    if (A2) {
        const float* Wb = W2 + (size_t)n * K2 * O;
        for (int k0 = 0; k0 < K2; k0 += 16) {
            for (int i = tid; i < 1024; i += 256) {
                int kk = i & 15, bb = i >> 4;
                int k = k0 + kk;
                sA[kk][bb] = (k < K2) ? A2[((size_t)(b0 + bb) * Nn + n) * K2 + k] : 0.f;
            }
            for (int i = tid; i < 1024; i += 256) {
                int oo = i & 63, kk = i >> 6;
                int k = k0 + kk;
                sW[kk][oo] = (k < K2) ? Wb[(size_t)k * O + o0 + oo] : 0.f;
            }
            __syncthreads();
#pragma unroll
            for (int kk = 0; kk < 16; kk++) {
                float a[4], w[4];
#pragma unroll
                for (int i = 0; i < 4; i++) a[i] = sA[kk][threadIdx.y + i * 16];
#pragma unroll
                for (int j = 0; j < 4; j++) w[j] = sW[kk][threadIdx.x + j * 16];
#pragma unroll
                for (int i = 0; i < 4; i++)
#pragma unroll
                    for (int j = 0; j < 4; j++) acc[i][j] += a[i] * w[j];
            }
            __syncthreads();
        }
    }
    // ---- epilogue ----
    const float* bp = bias ? (sharedwb ? bias : bias + (size_t)n * O) : nullptr;
#pragma unroll
    for (int i = 0; i < 4; i++) {
        int b = b0 + threadIdx.y + i * 16;
#pragma unroll
        for (int j = 0; j < 4; j++) {
            int o = o0 + threadIdx.x + j * 16;
            float v = acc[i][j];
            if (bp) v += bp[o];
            Y[((size_t)b * Nn + n) * O + o] = v;
        }
    }
}

// ---------------------------------------------------------------------------
// G-mix over nodes + LSTM pointwise, in-place on h,c.
// Ypre: (B,N,512) pre-mix gates (i|f|g|o each 128). grid: (B, 2) j-tiles of 64.
// ---------------------------------------------------------------------------
__global__ __launch_bounds__(256) void mixlstm(
    const float* __restrict__ Ypre, const float* __restrict__ G,
    float* __restrict__ h, float* __restrict__ c)
{
    const int b = blockIdx.x;
    const int jt = blockIdx.y * 64;
    const int tid = threadIdx.x;
    __shared__ float sY[24 * 4 * 64];  // n, gate, j
    __shared__ float sG[576];
    for (int i = tid; i < 576; i += 256) sG[i] = G[i];
    for (int i = tid; i < 6144; i += 256) {
        int j = i & 63, g = (i >> 6) & 3, n = i >> 8;
        sY[i] = Ypre[((size_t)b * 24 + n) * 512 + g * 128 + jt + j];
    }
    __syncthreads();
    for (int w = tid; w < 1536; w += 256) {
        int j = w & 63, m = w >> 6;
        float gi = 0.f, gf = 0.f, gg = 0.f, go = 0.f;
        const float* gr = &sG[m * 24];
#pragma unroll
        for (int n = 0; n < 24; n++) {
            float g = gr[n];
            gi += g * sY[n * 256 + j];
            gf += g * sY[n * 256 + 64 + j];
            gg += g * sY[n * 256 + 128 + j];
            go += g * sY[n * 256 + 192 + j];
        }
        size_t idx = ((size_t)b * 24 + m) * 128 + jt + j;
        float cv = c[idx];
        float si = 1.f / (1.f + expf(-gi));
        float sf = 1.f / (1.f + expf(-gf));
        float so = 1.f / (1.f + expf(-go));
        float tg = tanhf(gg);
        cv = sf * cv + si * tg;
        c[idx] = cv;
        h[idx] = so * tanhf(cv);
    }
}

// ---------------------------------------------------------------------------
// Init mix: h0 = G*Yh, c0 = G*Yc, broadcast into both LSTM layers' states.
// ---------------------------------------------------------------------------
__global__ __launch_bounds__(256) void mix_init(
    const float* __restrict__ Yh, const float* __restrict__ Yc,
    const float* __restrict__ G,
    float* __restrict__ h1, float* __restrict__ c1,
    float* __restrict__ h2, float* __restrict__ c2)
{
    const int b = blockIdx.x;
    const int tid = threadIdx.x;
    __shared__ float sYh[3072], sYc[3072], sG[576];
    for (int i = tid; i < 576; i += 256) sG[i] = G[i];
    for (int i = tid; i < 3072; i += 256) {
        sYh[i] = Yh[(size_t)b * 3072 + i];
        sYc[i] = Yc[(size_t)b * 3072 + i];
    }
    __syncthreads();
    for (int w = tid; w < 3072; w += 256) {
        int o = w & 127, m = w >> 7;
        float ah = 0.f, ac = 0.f;
#pragma unroll
        for (int n = 0; n < 24; n++) {
            float g = sG[m * 24 + n];
            ah += g * sYh[n * 128 + o];
            ac += g * sYc[n * 128 + o];
        }
        size_t idx = (size_t)b * 3072 + w;
        h1[idx] = ah; h2[idx] = ah;
        c1[idx] = ac; c2[idx] = ac;
    }
}

// ---------------------------------------------------------------------------
// xi0 = concat(z, x) per (b,n); loc_start = x[...,:4]
// ---------------------------------------------------------------------------
__global__ __launch_bounds__(256) void init_xi(
    const float* __restrict__ x, const float* __restrict__ z,
    float* __restrict__ xi, float* __restrict__ ls)
{
    int idx = blockIdx.x * 256 + threadIdx.x;
    const int total = Bsz * Nn * 72;
    if (idx < total) {
        int bn = idx / 72, k = idx - bn * 72;
        xi[idx] = (k < 64) ? z[(size_t)bn * 64 + k] : x[(size_t)bn * 8 + (k - 64)];
    }
    if (idx < Bsz * Nn * 4) {
        int bn = idx >> 2, j = idx & 3;
        ls[idx] = x[(size_t)bn * 8 + j];
    }
}

// ---------------------------------------------------------------------------
// Final per-step kernel: mix fc outputs + tanh, head matmuls (+bias), second
// G-mix, quaternion normalize + multiply, write outputs, update xi & loc_start.
// One block per batch element.
// ---------------------------------------------------------------------------
__global__ __launch_bounds__(256) void finstep(
    const float* __restrict__ P1, const float* __restrict__ P2,
    const float* __restrict__ G,
    const float* __restrict__ locW, const float* __restrict__ locb,
    const float* __restrict__ lzW, const float* __restrict__ lzb,
    float* __restrict__ ls, float* __restrict__ xi,
    float* __restrict__ out, int t)
{
    const int b = blockIdx.x;
    const int tid = threadIdx.x;
    __shared__ float sP1[3072], sP2[3072], sY1[3072], sY2[3072];
    __shared__ float sG[576];
    __shared__ float sLp[24][3], sZp[24][4], sL3[24][3], sZ3[24][4];
    for (int i = tid; i < 576; i += 256) sG[i] = G[i];
    for (int i = tid; i < 3072; i += 256) {
        sP1[i] = P1[(size_t)b * 3072 + i];
        sP2[i] = P2[(size_t)b * 3072 + i];
    }
    __syncthreads();
    // yi1 = tanh(G*P1), yi2 = tanh(G*P2)
    for (int w = tid; w < 3072; w += 256) {
        int o = w & 127, m = w >> 7;
        float a1 = 0.f, a2 = 0.f;
#pragma unroll
        for (int n = 0; n < 24; n++) {
            float g = sG[m * 24 + n];
            a1 += g * sP1[n * 128 + o];
            a2 += g * sP2[n * 128 + o];
        }
        sY1[w] = tanhf(a1);
        sY2[w] = tanhf(a2);
    }
    __syncthreads();
    // heads (bias added pre-mix per graph_linear)
    if (tid < 72) {
        int m = tid / 3, j = tid - m * 3;
        float s = locb[j];
        for (int o = 0; o < 128; o++) s += sY1[m * 128 + o] * locW[o * 3 + j];
        sLp[m][j] = s;
    } else if (tid < 168) {
        int w2 = tid - 72; int m = w2 >> 2, j = w2 & 3;
        float s = lzb[j];
        for (int o = 0; o < 128; o++) s += sY2[m * 128 + o] * lzW[o * 4 + j];
        sZp[m][j] = s;
    }
    __syncthreads();
    // second G-mix
    if (tid < 72) {
        int m = tid / 3, j = tid - m * 3;
        float s = 0.f;
#pragma unroll
        for (int n = 0; n < 24; n++) s += sG[m * 24 + n] * sLp[n][j];
        sL3[m][j] = s;
    } else if (tid < 168) {
        int w2 = tid - 72; int m = w2 >> 2, j = w2 & 3;
        float s = 0.f;
#pragma unroll
        for (int n = 0; n < 24; n++) s += sG[m * 24 + n] * sZp[n][j];
        sZ3[m][j] = s;
    }
    __syncthreads();
    // quaternion update + outputs
    if (tid < 24) {
        int m = tid;
        float xw = 1.f, xx = sL3[m][0], xy = sL3[m][1], xz = sL3[m][2];
        float r = rsqrtf(xw * xw + xx * xx + xy * xy + xz * xz);
        float dw = xw * r, dx = xx * r, dy = xy * r, dz = xz * r;
        size_t li = ((size_t)b * 24 + m) * 4;
        float qw = ls[li], qx = ls[li + 1], qy = ls[li + 2], qz = ls[li + 3];
        float lw = qw * dw - qx * dx - qy * dy - qz * dz;
        float lx = qw * dx + qx * dw + qy * dz - qz * dy;
        float ly = qw * dy - qx * dz + qy * dw + qz * dx;
        float lz = qw * dz + qx * dy - qy * dx + qz * dw;
        size_t oi = (((size_t)b * Tt + t) * Nn + m) * 4;
        out[oi + 0] = lw; out[oi + 1] = lx; out[oi + 2] = ly; out[oi + 3] = lz;
        size_t zi = (size_t)Bsz * Tt * Nn * 4 + oi;
        out[zi + 0] = sZ3[m][0]; out[zi + 1] = sZ3[m][1];
        out[zi + 2] = sZ3[m][2]; out[zi + 3] = sZ3[m][3];
        ls[li] = lw; ls[li + 1] = lx; ls[li + 2] = ly; ls[li + 3] = lz;
        size_t xb = ((size_t)b * 24 + m) * 72 + 64;
        xi[xb + 0] = lw; xi[xb + 1] = lx; xi[xb + 2] = ly; xi[xb + 3] = lz;
        xi[xb + 4] = dw; xi[xb + 5] = dx; xi[xb + 6] = dy; xi[xb + 7] = dz;
    }
}

extern "C" void kernel_launch(void* const* d_in, const int* in_sizes, int n_in,
                              void* d_out, int out_size, void* d_ws, size_t ws_size,
                              hipStream_t stream)
{
    const float* x    = (const float*)d_in[0];
    const float* enc  = (const float*)d_in[1];
    const float* z    = (const float*)d_in[2];
    // d_in[3] = y (unused by reference)
    const float* G    = (const float*)d_in[4];
    const float* Wx0  = (const float*)d_in[5];
    const float* Wh0  = (const float*)d_in[6];
    const float* b0   = (const float*)d_in[7];
    const float* Wx1  = (const float*)d_in[8];
    const float* Wh1  = (const float*)d_in[9];
    const float* b1   = (const float*)d_in[10];
    const float* fcW  = (const float*)d_in[11];
    const float* fcb  = (const float*)d_in[12];
    const float* fc2W = (const float*)d_in[13];
    const float* fc2b = (const float*)d_in[14];
    const float* ih1W = (const float*)d_in[15];
    const float* ih1b = (const float*)d_in[16];
    const float* ih2W = (const float*)d_in[17];
    const float* ih2b = (const float*)d_in[18];
    const float* locW = (const float*)d_in[19];
    const float* locb = (const float*)d_in[20];
    const float* lzW  = (const float*)d_in[21];
    const float* lzb  = (const float*)d_in[22];
    float* out = (float*)d_out;

    float* ws = (float*)d_ws;
    const size_t BN = (size_t)Bsz * Nn;
    float* xi = ws;                 // BN*72
    float* h1 = xi + BN * 72;       // BN*128
    float* c1 = h1 + BN * 128;
    float* h2 = c1 + BN * 128;
    float* c2 = h2 + BN * 128;
    float* lsb = c2 + BN * 128;     // BN*4
    float* yp = lsb + BN * 4;       // BN*512 (gates pre-mix; reused for p1/p2)
    float* p1 = yp;                 // BN*128 (after yp consumed)
    float* p2 = yp + BN * 128;      // BN*128
    // total ws use: BN*(72+512+512+4) floats = ~54 MB

    dim3 blk(16, 16);

    // ---- init: h0/c0 (graph_linear of enc), xi0, loc_start ----
    gemm2in<<<dim3(2, 8, 24), blk, 0, stream>>>(enc, 256, nullptr, 0, ih1W, nullptr, ih1b, yp, 128, 1, 0);
    gemm2in<<<dim3(2, 8, 24), blk, 0, stream>>>(enc, 256, nullptr, 0, ih2W, nullptr, ih2b, yp + BN * 128, 128, 1, 0);
    mix_init<<<512, 256, 0, stream>>>(yp, yp + BN * 128, G, h1, c1, h2, c2);
    init_xi<<<3456, 256, 0, stream>>>(x, z, xi, lsb);

    // ---- T sequential steps ----
    for (int t = 0; t < Tt; t++) {
        gemm2in<<<dim3(8, 8, 24), blk, 0, stream>>>(xi, 72, h1, 128, Wx0, Wh0, b0, yp, 512, 0, 0);
        mixlstm<<<dim3(512, 2), 256, 0, stream>>>(yp, G, h1, c1);
        gemm2in<<<dim3(8, 8, 24), blk, 0, stream>>>(h1, 128, h2, 128, Wx1, Wh1, b1, yp, 512, 0, 0);
        mixlstm<<<dim3(512, 2), 256, 0, stream>>>(yp, G, h2, c2);
        gemm2in<<<dim3(2, 8, 24), blk, 0, stream>>>(h2, 128, nullptr, 0, fcW, nullptr, fcb, p1, 128, 0, 1);
        gemm2in<<<dim3(2, 8, 24), blk, 0, stream>>>(h2, 128, nullptr, 0, fc2W, nullptr, fc2b, p2, 128, 0, 1);
        finstep<<<512, 256, 0, stream>>>(p1, p2, G, locW, locb, lzW, lzb, lsb, xi, out, t);
    }
}

// Round 2
// 2486.407 us; speedup vs baseline: 3.1322x; 3.1322x over previous
//
#include <hip/hip_runtime.h>
#include <math.h>

#define Bsz 512
#define Nn  24
#define Tt  25
// IN=8, L=64, H=256, OUT=128; layer1 K=200 (pad->256), layer2 K=256, fc K=128

typedef _Float16 f16;
typedef _Float16 f16x8 __attribute__((ext_vector_type(8)));
typedef float f32x4 __attribute__((ext_vector_type(4)));

// ---------------------------------------------------------------------------
// MFMA fp16 GEMM, per-node block-diagonal:
//   Y[b,n,o] = sum_k A[b,n,k] * W[n,o,k] + bias[n,o]      (W pre-transposed)
// A16: (B,Nn,Ka) f16  (or A32 fp32 with on-the-fly convert, for enc init)
// W:   (Nn,O,Ka) f16, wstride = O*Ka (0 = shared across nodes)
// Block: 256 thr = 4 waves (2x2), wave tile (FM*32)x(FN*16)... block tile
//   BM=FM*32 rows x BN=FN*32 cols; each wave FM x FN frags of 16x16.
// grid: (O/(FN*32), Bsz/(FM*32), Nn)
// ---------------------------------------------------------------------------
template <int FM, int FN>
__global__ __launch_bounds__(256) void gemm_mfma(
    const f16* __restrict__ A16, const float* __restrict__ A32, int Ka,
    const f16* __restrict__ W, size_t wstride,
    const float* __restrict__ bias, int bstride,
    float* __restrict__ Y, int O)
{
    const int BM = FM * 32, BN = FN * 32;
    const int n  = blockIdx.z;
    const int b0 = blockIdx.y * BM;
    const int o0 = blockIdx.x * BN;
    const int tid  = threadIdx.x;
    const int wave = tid >> 6, lane = tid & 63;
    const int wm = (wave >> 1) * FM * 16;   // wave row offset in tile
    const int wn = (wave & 1) * FN * 16;    // wave col offset in tile
    const int m16 = lane & 15, quad = lane >> 4;

    __shared__ __attribute__((aligned(16))) f16 sA[BM][72];  // 64 K + 8 pad
    __shared__ __attribute__((aligned(16))) f16 sW[BN][72];

    const f16* Wn = W + (size_t)n * wstride;
    f32x4 acc[FM][FN] = {};

    const int r  = tid >> 3;          // staging row 0..31
    const int cc = (tid & 7) * 8;     // staging col (halfs), 16B chunks

    for (int k0 = 0; k0 < Ka; k0 += 64) {
        // ---- stage A tile ----
        if (A16) {
            for (int row = r; row < BM; row += 32) {
                const f16x8* src = (const f16x8*)&A16[((size_t)(b0 + row) * Nn + n) * Ka + k0 + cc];
                *(f16x8*)&sA[row][cc] = *src;
            }
        } else {
            for (int row = r; row < BM; row += 32) {
                const float* src = &A32[((size_t)(b0 + row) * Nn + n) * Ka + k0 + cc];
                f16x8 v;
#pragma unroll
                for (int u = 0; u < 8; u++) v[u] = (f16)src[u];
                *(f16x8*)&sA[row][cc] = v;
            }
        }
        // ---- stage W tile (rows = o, contiguous k) ----
        for (int row = r; row < BN; row += 32) {
            const f16x8* src = (const f16x8*)&Wn[(size_t)(o0 + row) * Ka + k0 + cc];
            *(f16x8*)&sW[row][cc] = *src;
        }
        __syncthreads();
#pragma unroll
        for (int kk = 0; kk < 64; kk += 32) {
            f16x8 af[FM], bf[FN];
#pragma unroll
            for (int i = 0; i < FM; i++)
                af[i] = *(const f16x8*)&sA[wm + i * 16 + m16][kk + quad * 8];
#pragma unroll
            for (int j = 0; j < FN; j++)
                bf[j] = *(const f16x8*)&sW[wn + j * 16 + m16][kk + quad * 8];
#pragma unroll
            for (int i = 0; i < FM; i++)
#pragma unroll
                for (int j = 0; j < FN; j++)
                    acc[i][j] = __builtin_amdgcn_mfma_f32_16x16x32_f16(af[i], bf[j], acc[i][j], 0, 0, 0);
        }
        __syncthreads();
    }
    // ---- epilogue: D[row][col], col = lane&15, row = quad*4 + reg ----
#pragma unroll
    for (int i = 0; i < FM; i++) {
#pragma unroll
        for (int j = 0; j < FN; j++) {
            int ocol = o0 + wn + j * 16 + m16;
            float bv = bias[(size_t)n * bstride + ocol];
#pragma unroll
            for (int rg = 0; rg < 4; rg++) {
                int brow = b0 + wm + i * 16 + quad * 4 + rg;
                Y[((size_t)brow * Nn + n) * O + ocol] = acc[i][j][rg] + bv;
            }
        }
    }
}

// ---------------------------------------------------------------------------
// Weight prep: Wt0[n][o][k] (512,256) = [Wx0 | Wh0 | 0], Wt1 = [Wx1 | Wh1]
// ---------------------------------------------------------------------------
__global__ __launch_bounds__(256) void prep_w01(
    const float* __restrict__ Wx0, const float* __restrict__ Wh0,
    const float* __restrict__ Wx1, const float* __restrict__ Wh1,
    f16* __restrict__ Wt0, f16* __restrict__ Wt1)
{
    size_t idx = (size_t)blockIdx.x * 256 + threadIdx.x;
    const size_t total = (size_t)Nn * 512 * 256;
    if (idx >= total) return;
    int k = idx & 255;
    size_t no = idx >> 8;
    int o = no & 511;
    int n = (int)(no >> 9);
    float v0 = 0.f;
    if (k < 72) v0 = Wx0[((size_t)n * 72 + k) * 512 + o];
    else if (k < 200) v0 = Wh0[((size_t)n * 128 + (k - 72)) * 512 + o];
    Wt0[idx] = (f16)v0;
    float v1 = (k < 128) ? Wx1[((size_t)n * 128 + k) * 512 + o]
                         : Wh1[((size_t)n * 128 + (k - 128)) * 512 + o];
    Wt1[idx] = (f16)v1;
}

// Wtf[n][o][k] (256,128): o<128 -> fcW, else fc2W
__global__ __launch_bounds__(256) void prep_wf(
    const float* __restrict__ fcW, const float* __restrict__ fc2W,
    f16* __restrict__ Wtf)
{
    size_t idx = (size_t)blockIdx.x * 256 + threadIdx.x;
    const size_t total = (size_t)Nn * 256 * 128;
    if (idx >= total) return;
    int k = idx & 127;
    size_t no = idx >> 7;
    int o = no & 255;
    int n = (int)(no >> 8);
    float v = (o < 128) ? fcW[((size_t)n * 128 + k) * 128 + o]
                        : fc2W[((size_t)n * 128 + k) * 128 + (o - 128)];
    Wtf[idx] = (f16)v;
}

// Wti[o][k] (256,256) = [ih1W | ih2W]^T ; bi (256) ; bcat (24,256)
__global__ __launch_bounds__(256) void prep_wi(
    const float* __restrict__ ih1W, const float* __restrict__ ih2W,
    const float* __restrict__ ih1b, const float* __restrict__ ih2b,
    const float* __restrict__ fcb, const float* __restrict__ fc2b,
    f16* __restrict__ Wti, float* __restrict__ bi, float* __restrict__ bcat)
{
    int idx = blockIdx.x * 256 + threadIdx.x;   // 65536
    int k = idx & 255, o = idx >> 8;
    Wti[idx] = (f16)((o < 128) ? ih1W[(size_t)k * 128 + o] : ih2W[(size_t)k * 128 + (o - 128)]);
    if (idx < 256) bi[idx] = (idx < 128) ? ih1b[idx] : ih2b[idx - 128];
    if (idx < Nn * 256) {
        int n = idx >> 8, oo = idx & 255;
        bcat[idx] = (oo < 128) ? fcb[n * 128 + oo] : fc2b[n * 128 + (oo - 128)];
    }
}

// xi_cat[b,n,0:64)=z, [64:72)=x, [200:256)=0 (middle filled by mix/lstm); ls=x[:4]
__global__ __launch_bounds__(256) void init_xi(
    const float* __restrict__ x, const float* __restrict__ z,
    f16* __restrict__ xi, float* __restrict__ ls)
{
    size_t idx = (size_t)blockIdx.x * 256 + threadIdx.x;
    const size_t total = (size_t)Bsz * Nn * 256;
    if (idx < total) {
        size_t bn = idx >> 8;
        int k = idx & 255;
        if (k < 64) xi[idx] = (f16)z[bn * 64 + k];
        else if (k < 72) xi[idx] = (f16)x[bn * 8 + (k - 64)];
        else if (k >= 200) xi[idx] = (f16)0.f;
    }
    if (idx < (size_t)Bsz * Nn * 4) {
        size_t bn = idx >> 2;
        int j = idx & 3;
        ls[idx] = x[bn * 8 + j];
    }
}

// ---------------------------------------------------------------------------
// Init mix: Yhc (B,N,256) = [h-pre | c-pre]; h0 -> xi_cat[72:200), l2cat[0:128),
// l2cat[128:256); c0 -> c1, c2 (fp32).
// ---------------------------------------------------------------------------
__global__ __launch_bounds__(256) void mix_init(
    const float* __restrict__ Yhc, const float* __restrict__ G,
    f16* __restrict__ xi_cat, f16* __restrict__ l2cat,
    float* __restrict__ c1, float* __restrict__ c2)
{
    const int b = blockIdx.x;
    const int tid = threadIdx.x;
    __shared__ float sY[6144], sG[576];
    for (int i = tid; i < 576; i += 256) sG[i] = G[i];
    for (int i = tid; i < 6144; i += 256) sY[i] = Yhc[(size_t)b * 6144 + i];
    __syncthreads();
    for (int w = tid; w < 3072; w += 256) {
        int o = w & 127, m = w >> 7;
        float ah = 0.f, ac = 0.f;
#pragma unroll
        for (int n = 0; n < 24; n++) {
            float g = sG[m * 24 + n];
            ah += g * sY[n * 256 + o];
            ac += g * sY[n * 256 + 128 + o];
        }
        size_t row = (size_t)b * 24 + m;
        f16 hf = (f16)ah;
        xi_cat[row * 256 + 72 + o] = hf;
        l2cat[row * 256 + o] = hf;
        l2cat[row * 256 + 128 + o] = hf;
        c1[row * 128 + o] = ac;
        c2[row * 128 + o] = ac;
    }
}

// ---------------------------------------------------------------------------
// G-mix + LSTM pointwise. Ypre (B,N,512) fp32 pre-mix gates. c fp32 in/out.
// h written as f16 to dstA (raw) and dstB (raw or tanh).
// ---------------------------------------------------------------------------
__global__ __launch_bounds__(256) void mixlstm(
    const float* __restrict__ Ypre, const float* __restrict__ G,
    float* __restrict__ c,
    f16* __restrict__ dstA, int strideA,
    f16* __restrict__ dstB, int strideB, int tanhB)
{
    const int b = blockIdx.x;
    const int jt = blockIdx.y * 64;
    const int tid = threadIdx.x;
    __shared__ float sY[24 * 4 * 64];
    __shared__ float sG[576];
    for (int i = tid; i < 576; i += 256) sG[i] = G[i];
    for (int i = tid; i < 6144; i += 256) {
        int j = i & 63, g = (i >> 6) & 3, n = i >> 8;
        sY[i] = Ypre[((size_t)b * 24 + n) * 512 + g * 128 + jt + j];
    }
    __syncthreads();
    for (int w = tid; w < 1536; w += 256) {
        int j = w & 63, m = w >> 6;
        float gi = 0.f, gf = 0.f, gg = 0.f, go = 0.f;
        const float* gr = &sG[m * 24];
#pragma unroll
        for (int n = 0; n < 24; n++) {
            float g = gr[n];
            gi += g * sY[n * 256 + j];
            gf += g * sY[n * 256 + 64 + j];
            gg += g * sY[n * 256 + 128 + j];
            go += g * sY[n * 256 + 192 + j];
        }
        int col = jt + j;
        size_t row = (size_t)b * 24 + m;
        float cv = c[row * 128 + col];
        float si = 1.f / (1.f + expf(-gi));
        float sf = 1.f / (1.f + expf(-gf));
        float so = 1.f / (1.f + expf(-go));
        float tg = tanhf(gg);
        cv = sf * cv + si * tg;
        c[row * 128 + col] = cv;
        float h = so * tanhf(cv);
        dstA[row * strideA + col] = (f16)h;
        dstB[row * strideB + col] = (f16)(tanhB ? tanhf(h) : h);
    }
}

// ---------------------------------------------------------------------------
// Final per-step: mix fc pre-acts + tanh, head matmuls, second mix, quat,
// write outputs, update xi (f16) & loc_start (fp32). One block per batch elem.
// p: (B,N,256) fp32 = [fc1-pre | fc2-pre]
// ---------------------------------------------------------------------------
__global__ __launch_bounds__(256) void finstep(
    const float* __restrict__ p, const float* __restrict__ G,
    const float* __restrict__ locW, const float* __restrict__ locb,
    const float* __restrict__ lzW, const float* __restrict__ lzb,
    float* __restrict__ ls, f16* __restrict__ xi,
    float* __restrict__ out, int t)
{
    const int b = blockIdx.x;
    const int tid = threadIdx.x;
    __shared__ float sP[6144], sY1[3072], sY2[3072];
    __shared__ float sG[576];
    __shared__ float sLp[24][3], sZp[24][4], sL3[24][3], sZ3[24][4];
    for (int i = tid; i < 576; i += 256) sG[i] = G[i];
    for (int i = tid; i < 6144; i += 256) sP[i] = p[(size_t)b * 6144 + i];
    __syncthreads();
    for (int w = tid; w < 3072; w += 256) {
        int o = w & 127, m = w >> 7;
        float a1 = 0.f, a2 = 0.f;
#pragma unroll
        for (int n = 0; n < 24; n++) {
            float g = sG[m * 24 + n];
            a1 += g * sP[n * 256 + o];
            a2 += g * sP[n * 256 + 128 + o];
        }
        sY1[w] = tanhf(a1);
        sY2[w] = tanhf(a2);
    }
    __syncthreads();
    if (tid < 72) {
        int m = tid / 3, j = tid - m * 3;
        float s = locb[j];
        for (int o = 0; o < 128; o++) s += sY1[m * 128 + o] * locW[o * 3 + j];
        sLp[m][j] = s;
    } else if (tid < 168) {
        int w2 = tid - 72; int m = w2 >> 2, j = w2 & 3;
        float s = lzb[j];
        for (int o = 0; o < 128; o++) s += sY2[m * 128 + o] * lzW[o * 4 + j];
        sZp[m][j] = s;
    }
    __syncthreads();
    if (tid < 72) {
        int m = tid / 3, j = tid - m * 3;
        float s = 0.f;
#pragma unroll
        for (int n = 0; n < 24; n++) s += sG[m * 24 + n] * sLp[n][j];
        sL3[m][j] = s;
    } else if (tid < 168) {
        int w2 = tid - 72; int m = w2 >> 2, j = w2 & 3;
        float s = 0.f;
#pragma unroll
        for (int n = 0; n < 24; n++) s += sG[m * 24 + n] * sZp[n][j];
        sZ3[m][j] = s;
    }
    __syncthreads();
    if (tid < 24) {
        int m = tid;
        float xx = sL3[m][0], xy = sL3[m][1], xz = sL3[m][2];
        float r = rsqrtf(1.f + xx * xx + xy * xy + xz * xz);
        float dw = r, dx = xx * r, dy = xy * r, dz = xz * r;
        size_t li = ((size_t)b * 24 + m) * 4;
        float qw = ls[li], qx = ls[li + 1], qy = ls[li + 2], qz = ls[li + 3];
        float lw = qw * dw - qx * dx - qy * dy - qz * dz;
        float lx = qw * dx + qx * dw + qy * dz - qz * dy;
        float ly = qw * dy - qx * dz + qy * dw + qz * dx;
        float lz = qw * dz + qx * dy - qy * dx + qz * dw;
        size_t oi = (((size_t)b * Tt + t) * Nn + m) * 4;
        out[oi + 0] = lw; out[oi + 1] = lx; out[oi + 2] = ly; out[oi + 3] = lz;
        size_t zi = (size_t)Bsz * Tt * Nn * 4 + oi;
        out[zi + 0] = sZ3[m][0]; out[zi + 1] = sZ3[m][1];
        out[zi + 2] = sZ3[m][2]; out[zi + 3] = sZ3[m][3];
        ls[li] = lw; ls[li + 1] = lx; ls[li + 2] = ly; ls[li + 3] = lz;
        size_t xb = ((size_t)b * 24 + m) * 256 + 64;
        xi[xb + 0] = (f16)lw; xi[xb + 1] = (f16)lx; xi[xb + 2] = (f16)ly; xi[xb + 3] = (f16)lz;
        xi[xb + 4] = (f16)dw; xi[xb + 5] = (f16)dx; xi[xb + 6] = (f16)dy; xi[xb + 7] = (f16)dz;
    }
}

extern "C" void kernel_launch(void* const* d_in, const int* in_sizes, int n_in,
                              void* d_out, int out_size, void* d_ws, size_t ws_size,
                              hipStream_t stream)
{
    const float* x    = (const float*)d_in[0];
    const float* enc  = (const float*)d_in[1];
    const float* z    = (const float*)d_in[2];
    const float* G    = (const float*)d_in[4];
    const float* Wx0  = (const float*)d_in[5];
    const float* Wh0  = (const float*)d_in[6];
    const float* b0   = (const float*)d_in[7];
    const float* Wx1  = (const float*)d_in[8];
    const float* Wh1  = (const float*)d_in[9];
    const float* b1   = (const float*)d_in[10];
    const float* fcW  = (const float*)d_in[11];
    const float* fcb  = (const float*)d_in[12];
    const float* fc2W = (const float*)d_in[13];
    const float* fc2b = (const float*)d_in[14];
    const float* ih1W = (const float*)d_in[15];
    const float* ih1b = (const float*)d_in[16];
    const float* ih2W = (const float*)d_in[17];
    const float* ih2b = (const float*)d_in[18];
    const float* locW = (const float*)d_in[19];
    const float* locb = (const float*)d_in[20];
    const float* lzW  = (const float*)d_in[21];
    const float* lzb  = (const float*)d_in[22];
    float* out = (float*)d_out;

    const size_t BN = (size_t)Bsz * Nn;
    char* wp = (char*)d_ws;
    size_t off = 0;
    auto carve = [&](size_t bytes) -> char* {
        char* pc = wp + off;
        off += (bytes + 255) & ~(size_t)255;
        return pc;
    };
    f16*   Wt0    = (f16*)carve((size_t)Nn * 512 * 256 * 2);
    f16*   Wt1    = (f16*)carve((size_t)Nn * 512 * 256 * 2);
    f16*   Wtf    = (f16*)carve((size_t)Nn * 256 * 128 * 2);
    f16*   Wti    = (f16*)carve((size_t)256 * 256 * 2);
    float* bcat   = (float*)carve((size_t)Nn * 256 * 4);
    float* bi     = (float*)carve(256 * 4);
    f16*   xi_cat = (f16*)carve(BN * 256 * 2);
    f16*   l2cat  = (f16*)carve(BN * 256 * 2);
    f16*   yib    = (f16*)carve(BN * 128 * 2);
    float* c1     = (float*)carve(BN * 128 * 4);
    float* c2     = (float*)carve(BN * 128 * 4);
    float* ls     = (float*)carve(BN * 4 * 4);
    float* yp     = (float*)carve(BN * 512 * 4);   // also Yhc / p alias

    // ---- one-time prep (per launch) ----
    prep_w01<<<(int)(((size_t)Nn * 512 * 256 + 255) / 256), 256, 0, stream>>>(Wx0, Wh0, Wx1, Wh1, Wt0, Wt1);
    prep_wf<<<(int)(((size_t)Nn * 256 * 128 + 255) / 256), 256, 0, stream>>>(fcW, fc2W, Wtf);
    prep_wi<<<256, 256, 0, stream>>>(ih1W, ih2W, ih1b, ih2b, fcb, fc2b, Wti, bi, bcat);
    init_xi<<<(int)((BN * 256 + 255) / 256), 256, 0, stream>>>(x, z, xi_cat, ls);

    // ---- init states: [h0|c0] GEMM from enc (fp32 A path), then mix ----
    gemm_mfma<2, 2><<<dim3(4, 8, 24), 256, 0, stream>>>(
        nullptr, enc, 256, Wti, 0, bi, 0, yp, 256);
    mix_init<<<512, 256, 0, stream>>>(yp, G, xi_cat, l2cat, c1, c2);

    // ---- T sequential steps ----
    for (int t = 0; t < Tt; t++) {
        gemm_mfma<2, 4><<<dim3(4, 8, 24), 256, 0, stream>>>(
            xi_cat, nullptr, 256, Wt0, (size_t)512 * 256, b0, 512, yp, 512);
        mixlstm<<<dim3(512, 2), 256, 0, stream>>>(yp, G, c1, xi_cat + 72, 256, l2cat, 256, 0);
        gemm_mfma<2, 4><<<dim3(4, 8, 24), 256, 0, stream>>>(
            l2cat, nullptr, 256, Wt1, (size_t)512 * 256, b1, 512, yp, 512);
        mixlstm<<<dim3(512, 2), 256, 0, stream>>>(yp, G, c2, l2cat + 128, 256, yib, 128, 1);
        gemm_mfma<2, 2><<<dim3(4, 8, 24), 256, 0, stream>>>(
            yib, nullptr, 128, Wtf, (size_t)256 * 128, bcat, 256, yp, 256);
        finstep<<<512, 256, 0, stream>>>(yp, G, locW, locb, lzW, lzb, ls, xi_cat, out, t);
    }
}

// Round 3
// 2478.673 us; speedup vs baseline: 3.1420x; 1.0031x over previous
//
#include <hip/hip_runtime.h>
#include <math.h>

#define Bsz 512
#define Nn  24
#define Tt  25
// IN=8, L=64, H=256, OUT=128
// layer1: per-step K = 8(loc,locd) + 128(h1) -> padded 192; z-part hoisted to base1
// layer2: K=256; fc: K=128; init: K=256 from enc (fp32)

typedef _Float16 f16;
typedef _Float16 f16x8 __attribute__((ext_vector_type(8)));
typedef _Float16 f16x4 __attribute__((ext_vector_type(4)));
typedef float f32x4 __attribute__((ext_vector_type(4)));

// ---------------------------------------------------------------------------
// MFMA fp16 GEMM, per-node block-diagonal, W-as-A orientation:
//   Y[b,n,o] = sum_k Act[b,n,k] * W[n,o,k] + bias[n,o] (+ base16[b,n,o])
// D rows = o (4 consecutive per lane -> f16x4 stores), cols = b.
// Act16 (B,Nn,Ka) f16, or Act32 fp32 (init path). W (Nn,O,Ka) f16 pre-transposed.
// Block 256 thr = 4 waves (2x2). Tile (FM*32 o) x (FN*32 b).
// grid: (O/(FM*32), Bsz/(FN*32), Nn)
// ---------------------------------------------------------------------------
template <int FM, int FN>
__global__ __launch_bounds__(256) void gemm_mfma(
    const f16* __restrict__ Act, const float* __restrict__ Act32, int Ka,
    const f16* __restrict__ W, size_t wstride,
    const float* __restrict__ bias, int bstride,
    const f16* __restrict__ base16,
    f16* __restrict__ Y, int O)
{
    const int BM = FM * 32, BN = FN * 32;
    const int n  = blockIdx.z;
    const int o0 = blockIdx.x * BM;
    const int b0 = blockIdx.y * BN;
    const int tid  = threadIdx.x;
    const int wave = tid >> 6, lane = tid & 63;
    const int wm = (wave >> 1) * FM * 16;   // o offset of wave
    const int wn = (wave & 1) * FN * 16;    // b offset of wave
    const int m16 = lane & 15, quad = lane >> 4;

    __shared__ __attribute__((aligned(16))) f16 sW[BM][72];  // o-rows, k-cols (+pad)
    __shared__ __attribute__((aligned(16))) f16 sB[BN][72];  // b-rows, k-cols

    const f16* Wn = W + (size_t)n * wstride;
    f32x4 acc[FM][FN] = {};

    const int r  = tid >> 3;        // staging row 0..31
    const int cc = (tid & 7) * 8;   // staging col (halfs)

    for (int k0 = 0; k0 < Ka; k0 += 64) {
        for (int row = r; row < BM; row += 32)
            *(f16x8*)&sW[row][cc] = *(const f16x8*)&Wn[(size_t)(o0 + row) * Ka + k0 + cc];
        if (Act) {
            for (int row = r; row < BN; row += 32)
                *(f16x8*)&sB[row][cc] = *(const f16x8*)&Act[((size_t)(b0 + row) * Nn + n) * Ka + k0 + cc];
        } else {
            for (int row = r; row < BN; row += 32) {
                const float* src = &Act32[((size_t)(b0 + row) * Nn + n) * Ka + k0 + cc];
                f16x8 v;
#pragma unroll
                for (int u = 0; u < 8; u++) v[u] = (f16)src[u];
                *(f16x8*)&sB[row][cc] = v;
            }
        }
        __syncthreads();
#pragma unroll
        for (int kk = 0; kk < 64; kk += 32) {
            f16x8 af[FM], bf[FN];
#pragma unroll
            for (int i = 0; i < FM; i++)
                af[i] = *(const f16x8*)&sW[wm + i * 16 + m16][kk + quad * 8];
#pragma unroll
            for (int j = 0; j < FN; j++)
                bf[j] = *(const f16x8*)&sB[wn + j * 16 + m16][kk + quad * 8];
#pragma unroll
            for (int i = 0; i < FM; i++)
#pragma unroll
                for (int j = 0; j < FN; j++)
                    acc[i][j] = __builtin_amdgcn_mfma_f32_16x16x32_f16(af[i], bf[j], acc[i][j], 0, 0, 0);
        }
        __syncthreads();
    }
    // epilogue: D[row=o][col=b]; per lane, regs = 4 consecutive o at quad*4
#pragma unroll
    for (int i = 0; i < FM; i++) {
        const int orow = o0 + wm + i * 16 + quad * 4;
        float4 bv = make_float4(0.f, 0.f, 0.f, 0.f);
        if (bias) bv = *(const float4*)&bias[(size_t)n * bstride + orow];
#pragma unroll
        for (int j = 0; j < FN; j++) {
            const int bcol = b0 + wn + j * 16 + m16;
            size_t yi = ((size_t)bcol * Nn + n) * (size_t)O + orow;
            float v0 = acc[i][j][0] + bv.x;
            float v1 = acc[i][j][1] + bv.y;
            float v2 = acc[i][j][2] + bv.z;
            float v3 = acc[i][j][3] + bv.w;
            if (base16) {
                f16x4 bb = *(const f16x4*)&base16[yi];
                v0 += (float)bb[0]; v1 += (float)bb[1];
                v2 += (float)bb[2]; v3 += (float)bb[3];
            }
            f16x4 o4; o4[0] = (f16)v0; o4[1] = (f16)v1; o4[2] = (f16)v2; o4[3] = (f16)v3;
            *(f16x4*)&Y[yi] = o4;
        }
    }
}

// ---------------------------------------------------------------------------
// Weight prep: Wz (24,512,64)=Wx0[:, :64, :]^T; Wt0 (24,512,192)=[Wx0[64:72]|Wh0|0]^T;
// Wt1 (24,512,256)=[Wx1|Wh1]^T
// ---------------------------------------------------------------------------
__global__ __launch_bounds__(256) void prep_w01(
    const float* __restrict__ Wx0, const float* __restrict__ Wh0,
    const float* __restrict__ Wx1, const float* __restrict__ Wh1,
    f16* __restrict__ Wz, f16* __restrict__ Wt0, f16* __restrict__ Wt1)
{
    size_t idx = (size_t)blockIdx.x * 256 + threadIdx.x;
    const size_t nz = (size_t)Nn * 512 * 64;       // 786432
    const size_t n0 = (size_t)Nn * 512 * 192;      // 2359296
    const size_t n1 = (size_t)Nn * 512 * 256;      // 3145728
    if (idx < nz) {
        int k = idx & 63; int o = (idx >> 6) & 511; int n = (int)(idx >> 15);
        Wz[idx] = (f16)Wx0[((size_t)n * 72 + k) * 512 + o];
    } else if (idx < nz + n0) {
        size_t i2 = idx - nz;
        int k = (int)(i2 % 192);
        size_t no = i2 / 192;
        int o = (int)(no & 511); int n = (int)(no >> 9);
        float v = 0.f;
        if (k < 8) v = Wx0[((size_t)n * 72 + 64 + k) * 512 + o];
        else if (k < 136) v = Wh0[((size_t)n * 128 + (k - 8)) * 512 + o];
        Wt0[i2] = (f16)v;
    } else if (idx < nz + n0 + n1) {
        size_t i3 = idx - nz - n0;
        int k = (int)(i3 & 255);
        size_t no = i3 >> 8;
        int o = (int)(no & 511); int n = (int)(no >> 9);
        float v = (k < 128) ? Wx1[((size_t)n * 128 + k) * 512 + o]
                            : Wh1[((size_t)n * 128 + (k - 128)) * 512 + o];
        Wt1[i3] = (f16)v;
    }
}

// Wtf (24,256,128): o<128 -> fcW^T, else fc2W^T
__global__ __launch_bounds__(256) void prep_wf(
    const float* __restrict__ fcW, const float* __restrict__ fc2W,
    f16* __restrict__ Wtf)
{
    size_t idx = (size_t)blockIdx.x * 256 + threadIdx.x;
    if (idx >= (size_t)Nn * 256 * 128) return;
    int k = (int)(idx & 127);
    size_t no = idx >> 7;
    int o = (int)(no & 255); int n = (int)(no >> 8);
    float v = (o < 128) ? fcW[((size_t)n * 128 + k) * 128 + o]
                        : fc2W[((size_t)n * 128 + k) * 128 + (o - 128)];
    Wtf[idx] = (f16)v;
}

// Wti (256,256) = [ih1W | ih2W]^T ; bi (256) ; bcat (24,256)
__global__ __launch_bounds__(256) void prep_wi(
    const float* __restrict__ ih1W, const float* __restrict__ ih2W,
    const float* __restrict__ ih1b, const float* __restrict__ ih2b,
    const float* __restrict__ fcb, const float* __restrict__ fc2b,
    f16* __restrict__ Wti, float* __restrict__ bi, float* __restrict__ bcat)
{
    int idx = blockIdx.x * 256 + threadIdx.x;   // 65536
    int k = idx & 255, o = idx >> 8;
    Wti[idx] = (f16)((o < 128) ? ih1W[(size_t)k * 128 + o] : ih2W[(size_t)k * 128 + (o - 128)]);
    if (idx < 256) bi[idx] = (idx < 128) ? ih1b[idx] : ih2b[idx - 128];
    if (idx < Nn * 256) {
        int n = idx >> 8, oo = idx & 255;
        bcat[idx] = (oo < 128) ? fcb[n * 128 + oo] : fc2b[n * 128 + (oo - 128)];
    }
}

// xi2[b,n,0:8)=x, [136:192)=0 ([8:136) = h1, filled by mix_init/mixlstm); ls=x[:4]
__global__ __launch_bounds__(256) void init_xi(
    const float* __restrict__ x, f16* __restrict__ xi2, float* __restrict__ ls)
{
    size_t idx = (size_t)blockIdx.x * 256 + threadIdx.x;
    const size_t total = (size_t)Bsz * Nn * 192;
    if (idx < total) {
        size_t bn = idx / 192;
        int k = (int)(idx - bn * 192);
        if (k < 8) xi2[idx] = (f16)x[bn * 8 + k];
        else if (k >= 136) xi2[idx] = (f16)0.f;
    }
    if (idx < (size_t)Bsz * Nn * 4) {
        size_t bn = idx >> 2;
        ls[idx] = x[bn * 8 + (idx & 3)];
    }
}

// ---------------------------------------------------------------------------
// Init mix: Yhc (B,N,256) f16 = [h-pre | c-pre]; h0 -> xi2[8:136), l2cat[0:128),
// l2cat[128:256); c0 -> c1, c2 (fp32).
// ---------------------------------------------------------------------------
__global__ __launch_bounds__(256) void mix_init(
    const f16* __restrict__ Yhc, const float* __restrict__ G,
    f16* __restrict__ xi2, f16* __restrict__ l2cat,
    float* __restrict__ c1, float* __restrict__ c2)
{
    const int b = blockIdx.x;
    const int tid = threadIdx.x;
    __shared__ float sY[6144], sG[576];
    for (int i = tid; i < 576; i += 256) sG[i] = G[i];
    for (int v = tid; v < 768; v += 256) {
        int c8 = (v & 31) * 8, n = v >> 5;
        f16x8 t = *(const f16x8*)&Yhc[((size_t)b * Nn + n) * 256 + c8];
        float* d = &sY[n * 256 + c8];
#pragma unroll
        for (int u = 0; u < 8; u++) d[u] = (float)t[u];
    }
    __syncthreads();
    for (int w = tid; w < 3072; w += 256) {
        int o = w & 127, m = w >> 7;
        float ah = 0.f, ac = 0.f;
#pragma unroll
        for (int n = 0; n < 24; n++) {
            float g = sG[m * 24 + n];
            ah += g * sY[n * 256 + o];
            ac += g * sY[n * 256 + 128 + o];
        }
        size_t row = (size_t)b * Nn + m;
        f16 hf = (f16)ah;
        xi2[row * 192 + 8 + o] = hf;
        l2cat[row * 256 + o] = hf;
        l2cat[row * 256 + 128 + o] = hf;
        c1[row * 128 + o] = ac;
        c2[row * 128 + o] = ac;
    }
}

// ---------------------------------------------------------------------------
// G-mix + LSTM pointwise. Ypre (B,N,512) f16 pre-mix gates. c fp32 in/out.
// h written f16 to dstA (raw) and dstB (raw or tanh). grid (B, 2 j-tiles).
// ---------------------------------------------------------------------------
__global__ __launch_bounds__(256) void mixlstm(
    const f16* __restrict__ Ypre, const float* __restrict__ G,
    float* __restrict__ c,
    f16* __restrict__ dstA, int strideA,
    f16* __restrict__ dstB, int strideB, int tanhB)
{
    const int b = blockIdx.x;
    const int jt = blockIdx.y * 64;
    const int tid = threadIdx.x;
    __shared__ float sY[6144];   // n, gate, j(64)
    __shared__ float sG[576];
    for (int i = tid; i < 576; i += 256) sG[i] = G[i];
    for (int v = tid; v < 768; v += 256) {
        int j8 = (v & 7) * 8, g = (v >> 3) & 3, n = v >> 5;
        f16x8 t = *(const f16x8*)&Ypre[((size_t)b * Nn + n) * 512 + g * 128 + jt + j8];
        float* d = &sY[n * 256 + g * 64 + j8];
#pragma unroll
        for (int u = 0; u < 8; u++) d[u] = (float)t[u];
    }
    __syncthreads();
    for (int w = tid; w < 1536; w += 256) {
        int j = w & 63, m = w >> 6;
        float gi = 0.f, gf = 0.f, gg = 0.f, go = 0.f;
        const float* gr = &sG[m * 24];
#pragma unroll
        for (int n = 0; n < 24; n++) {
            float g = gr[n];
            gi += g * sY[n * 256 + j];
            gf += g * sY[n * 256 + 64 + j];
            gg += g * sY[n * 256 + 128 + j];
            go += g * sY[n * 256 + 192 + j];
        }
        int col = jt + j;
        size_t row = (size_t)b * Nn + m;
        float cv = c[row * 128 + col];
        float si = 1.f / (1.f + expf(-gi));
        float sf = 1.f / (1.f + expf(-gf));
        float so = 1.f / (1.f + expf(-go));
        float tg = tanhf(gg);
        cv = sf * cv + si * tg;
        c[row * 128 + col] = cv;
        float h = so * tanhf(cv);
        dstA[row * strideA + col] = (f16)h;
        dstB[row * strideB + col] = (f16)(tanhB ? tanhf(h) : h);
    }
}

// ---------------------------------------------------------------------------
// Final per-step: mix fc pre-acts + tanh, head matvecs, second mix, quat,
// outputs, update xi2[0:8) & loc_start. p (B,N,256) f16 = [fc1-pre | fc2-pre].
// ---------------------------------------------------------------------------
__global__ __launch_bounds__(256) void finstep(
    const f16* __restrict__ p, const float* __restrict__ G,
    const float* __restrict__ locW, const float* __restrict__ locb,
    const float* __restrict__ lzW, const float* __restrict__ lzb,
    float* __restrict__ ls, f16* __restrict__ xi2,
    float* __restrict__ out, int t)
{
    const int b = blockIdx.x;
    const int tid = threadIdx.x;
    __shared__ float sP[6144], sY1[3072], sY2[3072];
    __shared__ float sG[576];
    __shared__ float sLp[24][3], sZp[24][4], sL3[24][3], sZ3[24][4];
    for (int i = tid; i < 576; i += 256) sG[i] = G[i];
    for (int v = tid; v < 768; v += 256) {
        int c8 = (v & 31) * 8, n = v >> 5;
        f16x8 tv = *(const f16x8*)&p[((size_t)b * Nn + n) * 256 + c8];
        float* d = &sP[n * 256 + c8];
#pragma unroll
        for (int u = 0; u < 8; u++) d[u] = (float)tv[u];
    }
    __syncthreads();
    for (int w = tid; w < 3072; w += 256) {
        int o = w & 127, m = w >> 7;
        float a1 = 0.f, a2 = 0.f;
#pragma unroll
        for (int n = 0; n < 24; n++) {
            float g = sG[m * 24 + n];
            a1 += g * sP[n * 256 + o];
            a2 += g * sP[n * 256 + 128 + o];
        }
        sY1[w] = tanhf(a1);
        sY2[w] = tanhf(a2);
    }
    __syncthreads();
    if (tid < 72) {
        int m = tid / 3, j = tid - m * 3;
        float s = locb[j];
        for (int o = 0; o < 128; o++) s += sY1[m * 128 + o] * locW[o * 3 + j];
        sLp[m][j] = s;
    } else if (tid < 168) {
        int w2 = tid - 72; int m = w2 >> 2, j = w2 & 3;
        float s = lzb[j];
        for (int o = 0; o < 128; o++) s += sY2[m * 128 + o] * lzW[o * 4 + j];
        sZp[m][j] = s;
    }
    __syncthreads();
    if (tid < 72) {
        int m = tid / 3, j = tid - m * 3;
        float s = 0.f;
#pragma unroll
        for (int n = 0; n < 24; n++) s += sG[m * 24 + n] * sLp[n][j];
        sL3[m][j] = s;
    } else if (tid < 168) {
        int w2 = tid - 72; int m = w2 >> 2, j = w2 & 3;
        float s = 0.f;
#pragma unroll
        for (int n = 0; n < 24; n++) s += sG[m * 24 + n] * sZp[n][j];
        sZ3[m][j] = s;
    }
    __syncthreads();
    if (tid < 24) {
        int m = tid;
        float xx = sL3[m][0], xy = sL3[m][1], xz = sL3[m][2];
        float r = rsqrtf(1.f + xx * xx + xy * xy + xz * xz);
        float dw = r, dx = xx * r, dy = xy * r, dz = xz * r;
        size_t li = ((size_t)b * Nn + m) * 4;
        float qw = ls[li], qx = ls[li + 1], qy = ls[li + 2], qz = ls[li + 3];
        float lw = qw * dw - qx * dx - qy * dy - qz * dz;
        float lx = qw * dx + qx * dw + qy * dz - qz * dy;
        float ly = qw * dy - qx * dz + qy * dw + qz * dx;
        float lz = qw * dz + qx * dy - qy * dx + qz * dw;
        size_t oi = (((size_t)b * Tt + t) * Nn + m) * 4;
        out[oi + 0] = lw; out[oi + 1] = lx; out[oi + 2] = ly; out[oi + 3] = lz;
        size_t zi = (size_t)Bsz * Tt * Nn * 4 + oi;
        out[zi + 0] = sZ3[m][0]; out[zi + 1] = sZ3[m][1];
        out[zi + 2] = sZ3[m][2]; out[zi + 3] = sZ3[m][3];
        ls[li] = lw; ls[li + 1] = lx; ls[li + 2] = ly; ls[li + 3] = lz;
        size_t xb = ((size_t)b * Nn + m) * 192;
        xi2[xb + 0] = (f16)lw; xi2[xb + 1] = (f16)lx; xi2[xb + 2] = (f16)ly; xi2[xb + 3] = (f16)lz;
        xi2[xb + 4] = (f16)dw; xi2[xb + 5] = (f16)dx; xi2[xb + 6] = (f16)dy; xi2[xb + 7] = (f16)dz;
    }
}

extern "C" void kernel_launch(void* const* d_in, const int* in_sizes, int n_in,
                              void* d_out, int out_size, void* d_ws, size_t ws_size,
                              hipStream_t stream)
{
    const float* x    = (const float*)d_in[0];
    const float* enc  = (const float*)d_in[1];
    const float* z    = (const float*)d_in[2];
    const float* G    = (const float*)d_in[4];
    const float* Wx0  = (const float*)d_in[5];
    const float* Wh0  = (const float*)d_in[6];
    const float* b0i  = (const float*)d_in[7];
    const float* Wx1  = (const float*)d_in[8];
    const float* Wh1  = (const float*)d_in[9];
    const float* b1i  = (const float*)d_in[10];
    const float* fcW  = (const float*)d_in[11];
    const float* fcb  = (const float*)d_in[12];
    const float* fc2W = (const float*)d_in[13];
    const float* fc2b = (const float*)d_in[14];
    const float* ih1W = (const float*)d_in[15];
    const float* ih1b = (const float*)d_in[16];
    const float* ih2W = (const float*)d_in[17];
    const float* ih2b = (const float*)d_in[18];
    const float* locW = (const float*)d_in[19];
    const float* locb = (const float*)d_in[20];
    const float* lzW  = (const float*)d_in[21];
    const float* lzb  = (const float*)d_in[22];
    float* out = (float*)d_out;

    const size_t BN = (size_t)Bsz * Nn;
    char* wp = (char*)d_ws;
    size_t off = 0;
    auto carve = [&](size_t bytes) -> char* {
        char* pc = wp + off;
        off += (bytes + 255) & ~(size_t)255;
        return pc;
    };
    f16*   Wz     = (f16*)carve((size_t)Nn * 512 * 64 * 2);
    f16*   Wt0    = (f16*)carve((size_t)Nn * 512 * 192 * 2);
    f16*   Wt1    = (f16*)carve((size_t)Nn * 512 * 256 * 2);
    f16*   Wtf    = (f16*)carve((size_t)Nn * 256 * 128 * 2);
    f16*   Wti    = (f16*)carve((size_t)256 * 256 * 2);
    float* bcat   = (float*)carve((size_t)Nn * 256 * 4);
    float* bi     = (float*)carve(256 * 4);
    f16*   base1  = (f16*)carve(BN * 512 * 2);
    f16*   xi2    = (f16*)carve(BN * 192 * 2);
    f16*   l2cat  = (f16*)carve(BN * 256 * 2);
    f16*   yib    = (f16*)carve(BN * 128 * 2);
    float* c1     = (float*)carve(BN * 128 * 4);
    float* c2     = (float*)carve(BN * 128 * 4);
    float* ls     = (float*)carve(BN * 4 * 4);
    f16*   yp     = (f16*)carve(BN * 512 * 2);
    f16*   pbuf   = (f16*)carve(BN * 256 * 2);

    // ---- one-time prep ----
    prep_w01<<<24576, 256, 0, stream>>>(Wx0, Wh0, Wx1, Wh1, Wz, Wt0, Wt1);
    prep_wf<<<3072, 256, 0, stream>>>(fcW, fc2W, Wtf);
    prep_wi<<<256, 256, 0, stream>>>(ih1W, ih2W, ih1b, ih2b, fcb, fc2b, Wti, bi, bcat);
    init_xi<<<9216, 256, 0, stream>>>(x, xi2, ls);

    // base1 = z . Wx0[:,:64,:] + b0    (constant over all T steps)
    gemm_mfma<2, 4><<<dim3(8, 4, 24), 256, 0, stream>>>(
        nullptr, z, 64, Wz, (size_t)512 * 64, b0i, 512, nullptr, base1, 512);
    // init states: [h0|c0] from enc
    gemm_mfma<2, 4><<<dim3(4, 4, 24), 256, 0, stream>>>(
        nullptr, enc, 256, Wti, 0, bi, 0, nullptr, yp, 256);
    mix_init<<<512, 256, 0, stream>>>(yp, G, xi2, l2cat, c1, c2);

    // ---- T sequential steps ----
    for (int t = 0; t < Tt; t++) {
        gemm_mfma<2, 4><<<dim3(8, 4, 24), 256, 0, stream>>>(
            xi2, nullptr, 192, Wt0, (size_t)512 * 192, nullptr, 0, base1, yp, 512);
        mixlstm<<<dim3(512, 2), 256, 0, stream>>>(yp, G, c1, xi2 + 8, 192, l2cat, 256, 0);
        gemm_mfma<2, 4><<<dim3(8, 4, 24), 256, 0, stream>>>(
            l2cat, nullptr, 256, Wt1, (size_t)512 * 256, b1i, 512, nullptr, yp, 512);
        mixlstm<<<dim3(512, 2), 256, 0, stream>>>(yp, G, c2, l2cat + 128, 256, yib, 128, 1);
        gemm_mfma<2, 4><<<dim3(4, 4, 24), 256, 0, stream>>>(
            yib, nullptr, 128, Wtf, (size_t)256 * 128, bcat, 256, nullptr, pbuf, 256);
        finstep<<<512, 256, 0, stream>>>(pbuf, G, locW, locb, lzW, lzb, ls, xi2, out, t);
    }
}